// Round 1
// baseline (161.010 us; speedup 1.0000x reference)
//
#include <hip/hip_runtime.h>

#define NBH    32          // B*H
#define SEQ    2048
#define DIM    64
#define QBLK   128
#define KBLK   64
#define NCHUNK (SEQ / KBLK)     // 32
#define RPW    32               // rows per wave

typedef __attribute__((ext_vector_type(4))) float f32x4;
typedef __attribute__((ext_vector_type(8))) short bf16x8;

__device__ __forceinline__ unsigned short f2bf(float f) {
    unsigned u = __builtin_bit_cast(unsigned, f);
    u += 0x7FFFu + ((u >> 16) & 1u);
    return (unsigned short)(u >> 16);
}

__global__ __launch_bounds__(256, 2)
void softmaxv_kernel(const float* __restrict__ scores,
                     const float* __restrict__ v,
                     float* __restrict__ out)
{
    __shared__ unsigned short p_lds[QBLK * 72];   // bf16 P tile, row stride 72 (pad)
    __shared__ float scale_lds[QBLK];
    __shared__ float l_lds[QBLK];

    const int tid  = threadIdx.x;
    const int w    = tid >> 6;        // wave 0..3
    const int lane = tid & 63;
    const int g    = lane >> 4;       // 0..3
    const int c    = lane & 15;       // 0..15

    const int bid = blockIdx.x;
    const int bh  = bid >> 4;         // 32 (b,h) pairs
    const int qb  = bid & 15;
    const int q0  = qb * QBLK;

    // score rows owned by this thread: q0 + w*32 + i*4 + g, i = 0..7; cols c*4..c*4+3 within chunk
    const float* sp = scores + ((size_t)bh * SEQ + q0 + w * RPW + g) * SEQ + c * 4;
    const float* vb = v + (size_t)bh * SEQ * DIM + c;

    float m[8], l[8];
#pragma unroll
    for (int i = 0; i < 8; ++i) { m[i] = -INFINITY; l[i] = 0.0f; }

    f32x4 acc[2][4];
#pragma unroll
    for (int qt = 0; qt < 2; ++qt)
#pragma unroll
        for (int dt = 0; dt < 4; ++dt) acc[qt][dt] = (f32x4)0.0f;

    // prefetch S chunk 0
    f32x4 sreg[8];
#pragma unroll
    for (int i = 0; i < 8; ++i)
        sreg[i] = *reinterpret_cast<const f32x4*>(sp + (size_t)(i * 4) * SEQ);

    for (int t = 0; t < NCHUNK; ++t) {
        // ---- prefetch next S chunk (HBM stream) ----
        f32x4 snext[8];
        if (t + 1 < NCHUNK) {
#pragma unroll
            for (int i = 0; i < 8; ++i)
                snext[i] = *reinterpret_cast<const f32x4*>(sp + (size_t)(i * 4) * SEQ + (t + 1) * KBLK);
        }

        // ---- V fragment raw loads for this chunk (L2-resident) ----
        // element: V[t*64 + ks*32 + g*8 + j][dt*16 + c]
        float vtmp[2][4][8];
        {
            const float* vp = vb + (size_t)(t * KBLK + g * 8) * DIM;
#pragma unroll
            for (int ks = 0; ks < 2; ++ks)
#pragma unroll
                for (int dt = 0; dt < 4; ++dt)
#pragma unroll
                    for (int j = 0; j < 8; ++j)
                        vtmp[ks][dt][j] = vp[(ks * 32 + j) * DIM + dt * 16];
        }

        // ---- online softmax on sreg (fp32, exact) ----
        float sc[8];
        uint2 pw[8];
#pragma unroll
        for (int i = 0; i < 8; ++i) {
            f32x4 s4 = sreg[i];
            float cmax = fmaxf(fmaxf(s4[0], s4[1]), fmaxf(s4[2], s4[3]));
            cmax = fmaxf(cmax, __shfl_xor(cmax, 1));
            cmax = fmaxf(cmax, __shfl_xor(cmax, 2));
            cmax = fmaxf(cmax, __shfl_xor(cmax, 4));
            cmax = fmaxf(cmax, __shfl_xor(cmax, 8));
            float mn  = fmaxf(m[i], cmax);
            float scl = __expf(m[i] - mn);      // exp(-inf)=0 on first chunk
            float p0 = __expf(s4[0] - mn);
            float p1 = __expf(s4[1] - mn);
            float p2 = __expf(s4[2] - mn);
            float p3 = __expf(s4[3] - mn);
            float ps = (p0 + p1) + (p2 + p3);
            ps += __shfl_xor(ps, 1);
            ps += __shfl_xor(ps, 2);
            ps += __shfl_xor(ps, 4);
            ps += __shfl_xor(ps, 8);
            l[i] = l[i] * scl + ps;
            m[i] = mn;
            sc[i] = scl;
            unsigned lo = (unsigned)f2bf(p0) | ((unsigned)f2bf(p1) << 16);
            unsigned hi = (unsigned)f2bf(p2) | ((unsigned)f2bf(p3) << 16);
            pw[i] = make_uint2(lo, hi);
        }

        // ---- convert V to bf16 fragments ----
        bf16x8 vfrag[2][4];
#pragma unroll
        for (int ks = 0; ks < 2; ++ks)
#pragma unroll
            for (int dt = 0; dt < 4; ++dt) {
                bf16x8 b;
#pragma unroll
                for (int j = 0; j < 8; ++j)
                    b[j] = (short)f2bf(vtmp[ks][dt][j]);
                vfrag[ks][dt] = b;
            }

        __syncthreads();   // previous chunk's MFMA reads of p_lds are done

        // ---- write P tile + scales ----
#pragma unroll
        for (int i = 0; i < 8; ++i) {
            int row = w * RPW + i * 4 + g;
            *reinterpret_cast<uint2*>(&p_lds[row * 72 + c * 4]) = pw[i];
            if (c == 0) scale_lds[row] = sc[i];
        }

        __syncthreads();

        // ---- rescale accumulators + MFMA ----
#pragma unroll
        for (int qt = 0; qt < 2; ++qt) {
            f32x4 smul;
#pragma unroll
            for (int r = 0; r < 4; ++r)
                smul[r] = scale_lds[w * RPW + qt * 16 + g * 4 + r];
#pragma unroll
            for (int dt = 0; dt < 4; ++dt) acc[qt][dt] *= smul;
#pragma unroll
            for (int ks = 0; ks < 2; ++ks) {
                const bf16x8 a = *reinterpret_cast<const bf16x8*>(
                    &p_lds[(w * RPW + qt * 16 + c) * 72 + ks * 32 + g * 8]);
#pragma unroll
                for (int dt = 0; dt < 4; ++dt)
                    acc[qt][dt] = __builtin_amdgcn_mfma_f32_16x16x32_bf16(
                        a, vfrag[ks][dt], acc[qt][dt], 0, 0, 0);
            }
        }

        // shift prefetched chunk into place
        if (t + 1 < NCHUNK) {
#pragma unroll
            for (int i = 0; i < 8; ++i) sreg[i] = snext[i];
        }
    }

    // ---- epilogue: normalize by l and store ----
#pragma unroll
    for (int i = 0; i < 8; ++i)
        if (c == 0) l_lds[w * RPW + i * 4 + g] = l[i];
    __syncthreads();

    float* op = out + ((size_t)bh * SEQ + q0 + w * RPW) * DIM;
#pragma unroll
    for (int qt = 0; qt < 2; ++qt) {
        float rl[4];
#pragma unroll
        for (int r = 0; r < 4; ++r)
            rl[r] = 1.0f / l_lds[w * RPW + qt * 16 + g * 4 + r];
#pragma unroll
        for (int dt = 0; dt < 4; ++dt)
#pragma unroll
            for (int r = 0; r < 4; ++r)
                op[(qt * 16 + g * 4 + r) * DIM + dt * 16 + c] = acc[qt][dt][r] * rl[r];
    }
}

extern "C" void kernel_launch(void* const* d_in, const int* in_sizes, int n_in,
                              void* d_out, int out_size, void* d_ws, size_t ws_size,
                              hipStream_t stream)
{
    const float* scores = (const float*)d_in[0];
    const float* v      = (const float*)d_in[1];
    float* out          = (float*)d_out;

    dim3 grid(NBH * (SEQ / QBLK));   // 512
    dim3 block(256);
    softmaxv_kernel<<<grid, block, 0, stream>>>(scores, v, out);
}

// Round 2
// 138.254 us; speedup vs baseline: 1.1646x; 1.1646x over previous
//
#include <hip/hip_runtime.h>
#include <hip/hip_bf16.h>

#define NBH     32          // B*H
#define SEQ     2048
#define DIM     64
#define QBLK    64
#define KBLK    64
#define NCHUNK  (SEQ / KBLK)     // 32
#define PSTRIDE 72               // P tile row stride in ushorts (pad 8)

typedef __attribute__((ext_vector_type(4))) float f32x4;
typedef __attribute__((ext_vector_type(8))) short bf16x8;

__device__ __forceinline__ unsigned short bfbits(float f) {
    return __builtin_bit_cast(unsigned short, __float2bfloat16(f));
}

// ---------------------------------------------------------------------------
// V prep: convert V (fp32) into MFMA-B-fragment-ordered bf16 in ws.
// Layout: ws[bh][t][ks][dt][lane][j] (16B per (lane)): element j is
//   V[bh][t*64 + ks*32 + (lane>>4)*8 + j][dt*16 + (lane&15)]
// Total: 32*32*2*4*64*16B = 8 MB.
// ---------------------------------------------------------------------------
__global__ __launch_bounds__(256)
void vprep_kernel(const float* __restrict__ v, unsigned short* __restrict__ wsv)
{
    const int blk = blockIdx.x;            // bh*32 + t
    const int bh  = blk >> 5, t = blk & 31;
    const float* vp = v + ((size_t)bh * SEQ + t * KBLK) * DIM;
    unsigned short* op = wsv + (size_t)blk * 4096;    // 8 KB per (bh,t)

    for (int fl = threadIdx.x; fl < 512; fl += 256) {
        const int ks = fl >> 8, dt = (fl >> 6) & 3, lane = fl & 63;
        const int g = lane >> 4, c = lane & 15;
        const float* sp = vp + (ks * 32 + g * 8) * DIM + dt * 16 + c;
        bf16x8 frag;
#pragma unroll
        for (int j = 0; j < 8; ++j)
            frag[j] = (short)bfbits(sp[j * DIM]);
        *reinterpret_cast<bf16x8*>(op + fl * 8) = frag;
    }
}

// ---------------------------------------------------------------------------
// Main kernel: streaming no-max softmax + bf16 MFMA PV.
// Block = 256 threads (4 waves), 64 q-rows; wave w owns rows w*16..w*16+15.
// ---------------------------------------------------------------------------
__global__ __launch_bounds__(256, 4)
void softmaxv_kernel(const float* __restrict__ scores,
                     const unsigned short* __restrict__ vfrags,
                     float* __restrict__ out)
{
    __shared__ unsigned short p_lds[2][QBLK * PSTRIDE];
    __shared__ float l_lds[QBLK];

    const int tid  = threadIdx.x;
    const int w    = tid >> 6;
    const int lane = tid & 63;
    const int g    = lane >> 4;       // 0..3
    const int c    = lane & 15;       // 0..15

    const int bid = blockIdx.x;
    const int bh  = bid >> 5;         // 0..31
    const int qb  = bid & 31;
    const int q0  = qb * QBLK;

    // S rows owned by this thread: q0 + w*16 + i*4 + g (i=0..3), cols c*4..c*4+3 per chunk
    const float* sp = scores + ((size_t)bh * SEQ + q0 + w * 16 + g) * SEQ + c * 4;
    const unsigned short* vb = vfrags + (size_t)bh * 32 * 4096 + lane * 8;

    float lsum[4] = {0.f, 0.f, 0.f, 0.f};
    f32x4 acc[4];
#pragma unroll
    for (int dt = 0; dt < 4; ++dt) acc[dt] = (f32x4)0.0f;

#define LOADS(dst, t)                                                          \
    {                                                                          \
        _Pragma("unroll")                                                      \
        for (int i = 0; i < 4; ++i)                                            \
            dst[i] = *reinterpret_cast<const f32x4*>(                          \
                sp + (size_t)(i * 4) * SEQ + (t) * KBLK);                      \
    }

    auto proc = [&](const f32x4 (&sreg)[4], int t, unsigned short* pbuf) {
        // V fragments for this chunk (L2-resident, fully coalesced)
        const unsigned short* vp = vb + t * 4096;
        bf16x8 vf[2][4];
#pragma unroll
        for (int ks = 0; ks < 2; ++ks)
#pragma unroll
            for (int dt = 0; dt < 4; ++dt)
                vf[ks][dt] = *reinterpret_cast<const bf16x8*>(vp + (ks * 4 + dt) * 512);

        // no-max softmax numerators + deferred denominator accumulation
#pragma unroll
        for (int i = 0; i < 4; ++i) {
            f32x4 s4 = sreg[i];
            float p0 = __expf(s4[0]);
            float p1 = __expf(s4[1]);
            float p2 = __expf(s4[2]);
            float p3 = __expf(s4[3]);
            lsum[i] += (p0 + p1) + (p2 + p3);
            unsigned lo = (unsigned)bfbits(p0) | ((unsigned)bfbits(p1) << 16);
            unsigned hi = (unsigned)bfbits(p2) | ((unsigned)bfbits(p3) << 16);
            const int row = w * 16 + i * 4 + g;
            *reinterpret_cast<uint2*>(&pbuf[row * PSTRIDE + c * 4]) = make_uint2(lo, hi);
        }

        __syncthreads();   // P writes visible; also orders reuse of this buffer (period-2)

        // PV MFMA
#pragma unroll
        for (int ks = 0; ks < 2; ++ks) {
            const bf16x8 a = *reinterpret_cast<const bf16x8*>(
                &pbuf[(w * 16 + c) * PSTRIDE + ks * 32 + g * 8]);
#pragma unroll
            for (int dt = 0; dt < 4; ++dt)
                acc[dt] = __builtin_amdgcn_mfma_f32_16x16x32_bf16(
                    a, vf[ks][dt], acc[dt], 0, 0, 0);
        }
    };

    f32x4 sA[4], sB[4];
    LOADS(sA, 0)
    for (int tt = 0; tt < NCHUNK / 2; ++tt) {
        const int t0 = 2 * tt, t1 = 2 * tt + 1;
        LOADS(sB, t1)
        proc(sA, t0, p_lds[0]);
        if (t1 + 1 < NCHUNK) LOADS(sA, t1 + 1)
        proc(sB, t1, p_lds[1]);
    }
#undef LOADS

    // ---- epilogue: reduce l across the 16-lane column groups, normalize, store
#pragma unroll
    for (int i = 0; i < 4; ++i) {
        float l = lsum[i];
        l += __shfl_xor(l, 1);
        l += __shfl_xor(l, 2);
        l += __shfl_xor(l, 4);
        l += __shfl_xor(l, 8);
        if (c == 0) l_lds[w * 16 + i * 4 + g] = l;
    }
    __syncthreads();

    float* op = out + ((size_t)bh * SEQ + q0 + w * 16) * DIM;
    float rl[4];
#pragma unroll
    for (int r = 0; r < 4; ++r)
        rl[r] = 1.0f / l_lds[w * 16 + g * 4 + r];
#pragma unroll
    for (int dt = 0; dt < 4; ++dt)
#pragma unroll
        for (int r = 0; r < 4; ++r)
            op[(g * 4 + r) * DIM + dt * 16 + c] = acc[dt][r] * rl[r];
}

extern "C" void kernel_launch(void* const* d_in, const int* in_sizes, int n_in,
                              void* d_out, int out_size, void* d_ws, size_t ws_size,
                              hipStream_t stream)
{
    const float* scores = (const float*)d_in[0];
    const float* v      = (const float*)d_in[1];
    float* out          = (float*)d_out;
    unsigned short* wsv = (unsigned short*)d_ws;   // 8 MB used (ws is ~2 GB)

    vprep_kernel<<<dim3(NBH * NCHUNK), dim3(256), 0, stream>>>(v, wsv);
    softmaxv_kernel<<<dim3(NBH * (SEQ / QBLK)), dim3(256), 0, stream>>>(scores, wsv, out);
}